// Round 1
// baseline (640.890 us; speedup 1.0000x reference)
//
#include <hip/hip_runtime.h>

#define NH  4
#define ATT 16
#define COL 64
#define AIS 64
#define SK  200
#define HD  (NH * ATT)        // 64
#define AST (AIS + 1)         // 65: LDS row stride, (k*65+j)%32=(k+j)%32 -> 2-way (free)

// ---------------------------------------------------------------------------
// Kernel A: qk[b][h][j] = 0.125 * sum_d (query[b]·Q)[h*16+d] * K[j][h*16+d]
// One block per batch element. Folds the 1/8 score scale into qk.
// ---------------------------------------------------------------------------
__global__ __launch_bounds__(256)
void qk_precompute(const float* __restrict__ query,
                   const float* __restrict__ Qw,
                   const float* __restrict__ Kw,
                   float* __restrict__ qk) {
    __shared__ float qv_s[COL];
    __shared__ float qh_s[HD];
    const int b = blockIdx.x;
    const int t = threadIdx.x;

    if (t < COL) qv_s[t] = query[(size_t)b * COL + t];
    __syncthreads();

    if (t < HD) {
        float acc = 0.f;
        #pragma unroll
        for (int c = 0; c < COL; ++c)
            acc = fmaf(qv_s[c], Qw[c * HD + t], acc);   // coalesced Q row reads
        qh_s[t] = acc;
    }
    __syncthreads();

    const int h = t >> 6;       // 0..3
    const int j = t & 63;       // 0..63
    float acc = 0.f;
    #pragma unroll
    for (int d = 0; d < ATT; ++d)
        acc = fmaf(qh_s[h * ATT + d], Kw[j * HD + h * ATT + d], acc);
    qk[(size_t)b * (NH * AIS) + t] = acc * 0.125f;      // coalesced write
}

// ---------------------------------------------------------------------------
// Kernel B: per batch element:
//   scores[h][k] = A[k,:]·qk[h,:]          (A staged in LDS, qk via s_load)
//   softmax over k per head (wave w owns head w)
//   w[h][j]   = sum_k p[h][k] * A[k][j]
//   out[h*16+d] = (sum_j w[h][j] * V[j][h*16+d]) / denom[h]
// LDS: 52000 + 3200 + 1024 + 16 = 56.3 KB -> 2 blocks/CU
// ---------------------------------------------------------------------------
__global__ __launch_bounds__(256, 2)
void attn_main(const float* __restrict__ action,
               const float* __restrict__ Vw,
               const float* __restrict__ qk,
               float* __restrict__ out) {
    __shared__ float A[SK * AST];          // 52000 B, row stride 65
    __shared__ float p_s[NH][SK];          // 3200 B
    __shared__ float w_s[NH * AIS];        // 1024 B
    __shared__ float invd_s[NH];

    const int b    = blockIdx.x;
    const int t    = threadIdx.x;
    const int lane = t & 63;
    const int wv   = t >> 6;

    // ---- stage action[b] (200x64 fp32) into LDS, float4 global loads ----
    const float4* act4 = (const float4*)(action + (size_t)b * (SK * AIS));
    #pragma unroll
    for (int i = 0; i < 13; ++i) {
        const int idx = i * 256 + t;            // float4 index, 3200 total
        if (idx < SK * AIS / 4) {
            const float4 v = act4[idx];
            const int e = idx << 2;
            const int k = e >> 6;
            const int j = e & 63;
            float* dst = &A[k * AST + j];
            dst[0] = v.x; dst[1] = v.y; dst[2] = v.z; dst[3] = v.w;
        }
    }
    __syncthreads();

    // ---- scores: thread t = key k (t < 200). qk reads are wave-uniform ----
    const float* qkb = qk + (size_t)b * (NH * AIS);
    if (t < SK) {
        float a0 = 0.f, a1 = 0.f, a2 = 0.f, a3 = 0.f;
        const int base = t * AST;
        #pragma unroll 8
        for (int j = 0; j < AIS; ++j) {
            const float a = A[base + j];        // bank (k+j)%32: 2-way, free
            a0 = fmaf(a, qkb[0 * AIS + j], a0); // uniform -> s_load
            a1 = fmaf(a, qkb[1 * AIS + j], a1);
            a2 = fmaf(a, qkb[2 * AIS + j], a2);
            a3 = fmaf(a, qkb[3 * AIS + j], a3);
        }
        p_s[0][t] = a0; p_s[1][t] = a1; p_s[2][t] = a2; p_s[3][t] = a3;
    }
    __syncthreads();

    // ---- softmax: wave wv owns head wv, 200 = 3*64 + 8 ----
    {
        const int h = wv;
        const float s0 = p_s[h][lane];
        const float s1 = p_s[h][lane + 64];
        const float s2 = p_s[h][lane + 128];
        const float s3 = (lane < SK - 192) ? p_s[h][192 + lane] : -1e30f;
        float m = fmaxf(fmaxf(s0, s1), fmaxf(s2, s3));
        #pragma unroll
        for (int off = 32; off; off >>= 1) m = fmaxf(m, __shfl_xor(m, off));
        const float e0 = __expf(s0 - m);
        const float e1 = __expf(s1 - m);
        const float e2 = __expf(s2 - m);
        const float e3 = (lane < SK - 192) ? __expf(s3 - m) : 0.f;
        p_s[h][lane]       = e0;
        p_s[h][lane + 64]  = e1;
        p_s[h][lane + 128] = e2;
        if (lane < SK - 192) p_s[h][192 + lane] = e3;
        float sum = e0 + e1 + e2 + e3;
        #pragma unroll
        for (int off = 32; off; off >>= 1) sum += __shfl_xor(sum, off);
        if (lane == 0) invd_s[h] = 1.f / sum;
    }
    __syncthreads();   // cross-lane LDS ordering before w-phase reads p_s

    // ---- w[h][j] = sum_k p[h][k] * A[k][j]; wave wv owns head wv ----
    {
        const int h = wv, j = lane;
        float acc = 0.f;
        #pragma unroll 4
        for (int k = 0; k < SK; ++k)
            acc = fmaf(p_s[h][k], A[k * AST + j], acc);  // p: broadcast; A: 2-way
        w_s[h * AIS + j] = acc;
    }
    __syncthreads();

    // ---- epilogue: out[b][o], o = h*16+d; V rows read coalesced (L2-hot) ----
    if (t < HD) {
        const int h = t >> 4;
        float acc = 0.f;
        #pragma unroll
        for (int j = 0; j < AIS; ++j)
            acc = fmaf(w_s[h * AIS + j], Vw[j * HD + t], acc);
        out[(size_t)b * HD + t] = acc * invd_s[h];
    }
}

// ---------------------------------------------------------------------------
extern "C" void kernel_launch(void* const* d_in, const int* in_sizes, int n_in,
                              void* d_out, int out_size, void* d_ws, size_t ws_size,
                              hipStream_t stream) {
    const float* query  = (const float*)d_in[0];   // [B,1,64]
    const float* action = (const float*)d_in[1];   // [B,200,64]
    const float* Qw     = (const float*)d_in[2];   // [64,64]
    const float* Kw     = (const float*)d_in[3];   // [64,64]
    const float* Vw     = (const float*)d_in[4];   // [64,64]
    float* outp = (float*)d_out;                   // [B,64]

    const int B = in_sizes[0] / COL;               // 8192
    float* qkbuf = (float*)d_ws;                   // B*256 floats = 8 MB scratch

    qk_precompute<<<B, 256, 0, stream>>>(query, Qw, Kw, qkbuf);
    attn_main<<<B, 256, 0, stream>>>(action, Vw, qkbuf, outp);
}

// Round 3
// 581.286 us; speedup vs baseline: 1.1025x; 1.1025x over previous
//
#include <hip/hip_runtime.h>

#define NH   4
#define ATT  16
#define COL  64
#define AIS  64
#define SK   200
#define HD   64
#define JP   32          // j-pairs per row
#define AROW 33          // uint (half2) stride per k row: bank=(k+jp)%32 -> 2-way free

typedef _Float16 half2v __attribute__((ext_vector_type(2)));
typedef unsigned int uint32;

static __device__ __forceinline__ half2v u2h(uint32 u) {
    union { uint32 u; half2v h; } x; x.u = u; return x.h;
}

// pack two f32 -> f16x2 as raw uint32 (cvt_pkrtz returns __fp16 vec -> bitcast via union)
static __device__ __forceinline__ uint32 pk_u32(float a, float b) {
#if __has_builtin(__builtin_amdgcn_cvt_pkrtz)
    union { decltype(__builtin_amdgcn_cvt_pkrtz(0.f, 0.f)) h; uint32 u; } x;
    x.h = __builtin_amdgcn_cvt_pkrtz(a, b);
    return x.u;
#else
    union { half2v h; uint32 u; } x;
    x.h.x = (_Float16)a; x.h.y = (_Float16)b;
    return x.u;
#endif
}

#if __has_builtin(__builtin_amdgcn_fdot2)
#define DOT2(a, b, c) __builtin_amdgcn_fdot2((a), (b), (c), false)
#else
#define DOT2(a, b, c) fmaf((float)(a).x, (float)(b).x, fmaf((float)(a).y, (float)(b).y, (c)))
#endif

// ---------------------------------------------------------------------------
// Kernel A: qk2[b][h*32+jp] = f16x2( 0.125*qh[h]·K[:,2jp], 0.125*qh[h]·K[:,2jp+1] )
// 4 batches per block. query reads are wave-uniform -> s_load; Qw/Kw L1-hot.
// ---------------------------------------------------------------------------
__global__ __launch_bounds__(256)
void qk_kernel(const float* __restrict__ query, const float* __restrict__ Qw,
               const float* __restrict__ Kw, uint32* __restrict__ qk2, int nb) {
    __shared__ float qh_s[HD];
    const int t = threadIdx.x;
    #pragma unroll
    for (int bb = 0; bb < 4; ++bb) {
        const int b = blockIdx.x * 4 + bb;
        if (b >= nb) break;                         // block-uniform guard
        const float* qb = query + (size_t)b * COL;  // uniform -> s_load
        if (t < HD) {
            float acc = 0.f;
            #pragma unroll
            for (int c = 0; c < COL; ++c)
                acc = fmaf(qb[c], Qw[c * HD + t], acc);
            qh_s[t] = acc;
        }
        __syncthreads();
        if (t < 128) {
            const int h = t >> 5, jp = t & 31;
            float a0 = 0.f, a1 = 0.f;
            #pragma unroll
            for (int d = 0; d < ATT; ++d) {
                const float q = qh_s[h * ATT + d];
                a0 = fmaf(q, Kw[(2 * jp)     * HD + h * ATT + d], a0);
                a1 = fmaf(q, Kw[(2 * jp + 1) * HD + h * ATT + d], a1);
            }
            qk2[(size_t)b * 128 + t] = pk_u32(a0 * 0.125f, a1 * 0.125f);
        }
        __syncthreads();
    }
}

// ---------------------------------------------------------------------------
// Kernel B: one block per batch.
//  stage A[b] as f16 pairs (26.4 KB, conflict-free stride 33)
//  scores: thread k, 32 dword reads, 4x fdot2/iter, qk via s_load (SMEM pipe)
//  softmax: wave h owns head h
//  w[h][j]: thread j shares each A read across 4 heads; k split over 4 waves
//  epilogue: out = (w/denom) · V, V rows L1-hot
// LDS ~34.8 KB -> 4 blocks/CU (16 waves/CU)
// ---------------------------------------------------------------------------
__global__ __launch_bounds__(256, 4)
void attn_kernel(const float* __restrict__ action, const float* __restrict__ Vw,
                 const uint32* __restrict__ qk2, float* __restrict__ out) {
    __shared__ uint32 A2[SK * AROW];      // 26400 B
    __shared__ float4 p4_s[SK];           // 3200 B
    __shared__ float4 wpart[4][64];       // 4096 B
    __shared__ float4 w4_s[64];           // 1024 B
    __shared__ float  invd_s[NH];

    const int b    = blockIdx.x;
    const int t    = threadIdx.x;
    const int lane = t & 63;
    const int wv   = t >> 6;

    // ---- stage action[b] (200x64 fp32) -> f16 pairs in LDS ----
    const float4* act4 = (const float4*)(action + (size_t)b * (SK * AIS));
    #pragma unroll
    for (int i = 0; i < 13; ++i) {
        const int idx = i * 256 + t;                 // float4 index, 3200 total
        if (idx < SK * AIS / 4) {
            const float4 v = act4[idx];
            const int k   = idx >> 4;                // 16 float4 per row
            const int jp0 = (idx & 15) * 2;          // 2 half2 per float4
            A2[k * AROW + jp0]     = pk_u32(v.x, v.y);
            A2[k * AROW + jp0 + 1] = pk_u32(v.z, v.w);
        }
    }
    __syncthreads();

    // ---- scores: thread t = key k; qk2 reads wave-uniform -> s_load ----
    const uint32* qkb = qk2 + (size_t)b * 128;
    if (t < SK) {
        float a0 = 0.f, a1 = 0.f, a2 = 0.f, a3 = 0.f;
        const int base = t * AROW;
        #pragma unroll 8
        for (int jp = 0; jp < JP; ++jp) {
            const half2v av = u2h(A2[base + jp]);    // bank (k+jp)%32: free
            a0 = DOT2(av, u2h(qkb[jp]),      a0);
            a1 = DOT2(av, u2h(qkb[32 + jp]), a1);
            a2 = DOT2(av, u2h(qkb[64 + jp]), a2);
            a3 = DOT2(av, u2h(qkb[96 + jp]), a3);
        }
        float4 s; s.x = a0; s.y = a1; s.z = a2; s.w = a3;
        p4_s[t] = s;                                  // ds_write_b128
    }
    __syncthreads();

    // ---- softmax: wave wv owns head wv; 200 = 3*64 + 8 ----
    {
        float* pf = (float*)p4_s;
        const int h = wv;
        const float s0 = pf[lane * 4 + h];
        const float s1 = pf[(lane + 64) * 4 + h];
        const float s2 = pf[(lane + 128) * 4 + h];
        const float s3 = (lane < SK - 192) ? pf[(lane + 192) * 4 + h] : -1e30f;
        float m = fmaxf(fmaxf(s0, s1), fmaxf(s2, s3));
        #pragma unroll
        for (int off = 32; off; off >>= 1) m = fmaxf(m, __shfl_xor(m, off));
        const float e0 = __expf(s0 - m);
        const float e1 = __expf(s1 - m);
        const float e2 = __expf(s2 - m);
        const float e3 = (lane < SK - 192) ? __expf(s3 - m) : 0.f;
        pf[lane * 4 + h]         = e0;
        pf[(lane + 64) * 4 + h]  = e1;
        pf[(lane + 128) * 4 + h] = e2;
        if (lane < SK - 192) pf[(lane + 192) * 4 + h] = e3;
        float sum = e0 + e1 + e2 + e3;
        #pragma unroll
        for (int off = 32; off; off >>= 1) sum += __shfl_xor(sum, off);
        if (lane == 0) invd_s[h] = 1.f / sum;
    }
    __syncthreads();

    // ---- w[h][j] = sum_k p[h][k]*A[k][j]; A read shared across heads,
    //      k range split across the 4 waves (50 each) ----
    {
        const int j  = lane;
        const int jp = j >> 1;
        const int k0 = wv * 50;
        float c0 = 0.f, c1 = 0.f, c2 = 0.f, c3 = 0.f;
        #pragma unroll 10
        for (int kk = 0; kk < 50; ++kk) {
            const int k = k0 + kk;
            const float4 p = p4_s[k];                 // uniform b128 (broadcast)
            const half2v av = u2h(A2[k * AROW + jp]); // 2-lane broadcast, free
            const float a = (j & 1) ? (float)av.y : (float)av.x;
            c0 = fmaf(p.x, a, c0);
            c1 = fmaf(p.y, a, c1);
            c2 = fmaf(p.z, a, c2);
            c3 = fmaf(p.w, a, c3);
        }
        float4 c; c.x = c0; c.y = c1; c.z = c2; c.w = c3;
        wpart[wv][j] = c;
    }
    __syncthreads();

    // ---- reduce partials, fold 1/denom ----
    if (t < 64) {
        const float4 r0 = wpart[0][t], r1 = wpart[1][t];
        const float4 r2 = wpart[2][t], r3 = wpart[3][t];
        float4 w;
        w.x = (r0.x + r1.x + r2.x + r3.x) * invd_s[0];
        w.y = (r0.y + r1.y + r2.y + r3.y) * invd_s[1];
        w.z = (r0.z + r1.z + r2.z + r3.z) * invd_s[2];
        w.w = (r0.w + r1.w + r2.w + r3.w) * invd_s[3];
        w4_s[t] = w;
    }
    __syncthreads();

    // ---- epilogue: out[b][o] = sum_j w[h][j] * V[j][o], o = h*16+d ----
    if (t < 64) {
        const int h = t >> 4;
        const float* wf = (const float*)w4_s;
        float acc = 0.f;
        #pragma unroll
        for (int j = 0; j < AIS; ++j)
            acc = fmaf(wf[j * 4 + h], Vw[j * HD + t], acc);
        out[(size_t)b * HD + t] = acc;
    }
}

// ---------------------------------------------------------------------------
extern "C" void kernel_launch(void* const* d_in, const int* in_sizes, int n_in,
                              void* d_out, int out_size, void* d_ws, size_t ws_size,
                              hipStream_t stream) {
    const float* query  = (const float*)d_in[0];   // [B,1,64]
    const float* action = (const float*)d_in[1];   // [B,200,64]
    const float* Qw     = (const float*)d_in[2];   // [64,64]
    const float* Kw     = (const float*)d_in[3];   // [64,64]
    const float* Vw     = (const float*)d_in[4];   // [64,64]
    float* outp = (float*)d_out;                   // [B,64]

    const int B = in_sizes[0] / COL;               // 8192
    uint32* qk2 = (uint32*)d_ws;                   // B*128 uints = 4 MB scratch

    qk_kernel<<<(B + 3) / 4, 256, 0, stream>>>(query, Qw, Kw, qk2, B);
    attn_kernel<<<B, 256, 0, stream>>>(action, Vw, qk2, outp);
}